// Round 1
// baseline (2281.908 us; speedup 1.0000x reference)
//
#include <hip/hip_runtime.h>

#define BB 4
#define CC 256
#define HH 128
#define WW 128
#define NN (HH*WW)
#define EPSF 1e-10f

__device__ __forceinline__ float delu_f(float v) {
    // x>0: 10x+1 ; x<=0: exp(10x)
    return v > 0.0f ? fmaf(10.0f, v, 1.0f) : __expf(10.0f * v);
}

// ---------------- weight repack: wd3 (O,I,3,3) -> 12-float aligned rows, wd1 folded into center tap
__global__ __launch_bounds__(256) void k_prep_w(const float* __restrict__ wd1,
                                                const float* __restrict__ wd3,
                                                float* __restrict__ wpack)
{
    int idx = blockIdx.x * 256 + threadIdx.x;   // (oc*CC + c), 0..65535
    if (idx >= CC*CC) return;
    float w[12];
    #pragma unroll
    for (int k=0;k<9;k++) w[k] = wd3[(size_t)idx*9 + k];
    w[4] += wd1[idx];
    w[9]=0.0f; w[10]=0.0f; w[11]=0.0f;
    float4* o = (float4*)&wpack[(size_t)idx*12];
    o[0] = make_float4(w[0],w[1],w[2],w[3]);
    o[1] = make_float4(w[4],w[5],w[6],w[7]);
    o[2] = make_float4(w[8],w[9],w[10],w[11]);
}

// ---------------- shared GEMM register tile: 4 oc x 16 pos, K=256, x tile in LDS (xs[256][64])
__device__ __forceinline__ void gemm_tile_256(const float* __restrict__ w,
                                              const float* __restrict__ bias,
                                              const float* xs, int oc0, int j0,
                                              float acc[4][16])
{
    #pragma unroll
    for (int i=0;i<4;i++) {
        float bv = bias[oc0+i];
        #pragma unroll
        for (int j=0;j<16;j++) acc[i][j] = bv;
    }
    for (int c=0;c<CC;c+=4) {
        float4 wr[4];
        #pragma unroll
        for (int i=0;i<4;i++) wr[i] = *(const float4*)&w[(size_t)(oc0+i)*CC + c];
        #pragma unroll
        for (int cc=0;cc<4;cc++) {
            const float4* xr = (const float4*)&xs[(c+cc)*64 + j0];
            float xv[16];
            #pragma unroll
            for (int q=0;q<4;q++) { float4 t = xr[q];
                xv[4*q]=t.x; xv[4*q+1]=t.y; xv[4*q+2]=t.z; xv[4*q+3]=t.w; }
            #pragma unroll
            for (int i=0;i<4;i++) {
                float wv = (cc==0)?wr[i].x:(cc==1)?wr[i].y:(cc==2)?wr[i].z:wr[i].w;
                #pragma unroll
                for (int j=0;j<16;j++) acc[i][j] = fmaf(wv, xv[j], acc[i][j]);
            }
        }
    }
}

// ---------------- q' and k' projections + Qs = sum_m delu(q); k' = delu(k) to ws
__global__ __launch_bounds__(256) void k_qk(const float* __restrict__ x,
    const float* __restrict__ wq, const float* __restrict__ bq,
    const float* __restrict__ wk, const float* __restrict__ bk,
    float* __restrict__ kp, float* __restrict__ Qs)
{
    __shared__ float xs[CC*64];
    const int n0 = blockIdx.x * 64;
    const int b  = blockIdx.y;
    const int tid = threadIdx.x;
    const float* xb = x + (size_t)b*CC*NN;
    for (int i = tid*4; i < CC*64; i += 1024) {
        int c = i >> 6, j = i & 63;
        *(float4*)&xs[i] = *(const float4*)&xb[(size_t)c*NN + n0 + j];
    }
    __syncthreads();
    const int ocq = tid & 63, jg = tid >> 6;
    const int oc0 = ocq*4, j0 = jg*16;
    float acc[4][16];

    // Q phase
    gemm_tile_256(wq, bq, xs, oc0, j0, acc);
    float qs[16];
    #pragma unroll
    for (int j=0;j<16;j++) {
        float s = delu_f(acc[0][j]) + delu_f(acc[1][j]) + delu_f(acc[2][j]) + delu_f(acc[3][j]);
        #pragma unroll
        for (int m=1; m<64; m<<=1) s += __shfl_xor(s, m, 64);
        qs[j] = s;   // full sum over all 256 channels (wave = 64 lanes x 4 oc each)
    }
    if ((tid & 63) == 0) {
        #pragma unroll
        for (int j=0;j<16;j++) Qs[(size_t)b*NN + n0 + j0 + j] = qs[j];
    }

    // K phase
    gemm_tile_256(wk, bk, xs, oc0, j0, acc);
    #pragma unroll
    for (int i=0;i<4;i++) {
        float* kr = kp + ((size_t)b*CC + oc0 + i)*NN + n0 + j0;
        #pragma unroll
        for (int q=0;q<4;q++) {
            float4 o;
            o.x = delu_f(acc[i][4*q+0]); o.y = delu_f(acc[i][4*q+1]);
            o.z = delu_f(acc[i][4*q+2]); o.w = delu_f(acc[i][4*q+3]);
            *(float4*)&kr[4*q] = o;
        }
    }
}

// ---------------- Esum[b,c] = sum_n Qs[b,n] * k'[b,c,n]
__global__ __launch_bounds__(256) void k_esum(const float* __restrict__ kp,
    const float* __restrict__ Qs, float* __restrict__ Es)
{
    const int c = blockIdx.x & (CC-1), b = blockIdx.x >> 8;
    const int tid = threadIdx.x;
    const float4* kr = (const float4*)(kp + ((size_t)b*CC + c)*NN);
    const float4* qr = (const float4*)(Qs + (size_t)b*NN);
    float s = 0.0f;
    for (int i = tid; i < NN/4; i += 256) {
        float4 kk = kr[i], qq = qr[i];
        s += kk.x*qq.x + kk.y*qq.y + kk.z*qq.z + kk.w*qq.w;
    }
    #pragma unroll
    for (int m=1; m<64; m<<=1) s += __shfl_xor(s, m, 64);
    __shared__ float red[4];
    if ((tid & 63) == 0) red[tid >> 6] = s;
    __syncthreads();
    if (tid == 0) Es[b*CC + c] = red[0] + red[1] + red[2] + red[3];
}

// ---------------- rnorm[b,n] = 1 / (sum_c Es[b,c]*k'[b,c,n] + eps)
__global__ __launch_bounds__(256) void k_norm(const float* __restrict__ kp,
    const float* __restrict__ Es, float* __restrict__ rn)
{
    const int b = blockIdx.y;
    const int n0 = blockIdx.x * 256;
    const int tid = threadIdx.x;
    __shared__ float es[CC];
    es[tid] = Es[b*CC + tid];
    __syncthreads();
    float a = 0.0f;
    const float* kb = kp + (size_t)b*CC*NN + n0 + tid;
    #pragma unroll 8
    for (int c=0;c<CC;c++) a = fmaf(es[c], kb[(size_t)c*NN], a);
    rn[(size_t)b*NN + n0 + tid] = 1.0f / (a + EPSF);
}

// ---------------- v projection + attention epilogue: out = x + g*Es*k'*v*rn
__global__ __launch_bounds__(256) void k_vattn(const float* __restrict__ x,
    const float* __restrict__ wv, const float* __restrict__ bv,
    const float* __restrict__ kp, const float* __restrict__ Es,
    const float* __restrict__ rn, const float* __restrict__ gamma,
    float* __restrict__ out)
{
    __shared__ float xs[CC*64];
    const int n0 = blockIdx.x * 64;
    const int b  = blockIdx.y;
    const int tid = threadIdx.x;
    const float* xb = x + (size_t)b*CC*NN;
    for (int i = tid*4; i < CC*64; i += 1024) {
        int c = i >> 6, j = i & 63;
        *(float4*)&xs[i] = *(const float4*)&xb[(size_t)c*NN + n0 + j];
    }
    __syncthreads();
    const int ocq = tid & 63, jg = tid >> 6;
    const int oc0 = ocq*4, j0 = jg*16;
    float acc[4][16];
    gemm_tile_256(wv, bv, xs, oc0, j0, acc);
    const float g = gamma[0];
    #pragma unroll
    for (int i=0;i<4;i++) {
        const int oc = oc0 + i;
        const float eg = Es[b*CC + oc] * g;
        const float* kr = kp + ((size_t)b*CC + oc)*NN + n0 + j0;
        const float* rr = rn + (size_t)b*NN + n0 + j0;
        const float* xr = xs + oc*64 + j0;
        float* orow = out + ((size_t)b*CC + oc)*NN + n0 + j0;
        #pragma unroll
        for (int q=0;q<4;q++) {
            float4 kk = *(const float4*)&kr[4*q];
            float4 rv = *(const float4*)&rr[4*q];
            float4 xv = *(const float4*)&xr[4*q];
            float4 o;
            o.x = fmaf(eg*kk.x*rv.x, acc[i][4*q+0], xv.x);
            o.y = fmaf(eg*kk.y*rv.y, acc[i][4*q+1], xv.y);
            o.z = fmaf(eg*kk.z*rv.z, acc[i][4*q+2], xv.z);
            o.w = fmaf(eg*kk.w*rv.w, acc[i][4*q+3], xv.w);
            *(float4*)&orow[4*q] = o;
        }
    }
}

// ---------------- 3x3 conv (+folded 1x1): out += g * conv(x)
__global__ __launch_bounds__(256) void k_conv(const float* __restrict__ x,
    const float* __restrict__ wpack, const float* __restrict__ bd1,
    const float* __restrict__ bd3, const float* __restrict__ gamma,
    float* __restrict__ out)
{
    __shared__ float xsh[8*4*132];   // 8 in-ch x 4 rows x (128 + halo + pad)
    const int ocb = blockIdx.x;      // 0..3
    const int h0  = blockIdx.y * 2;  // row pair
    const int b   = blockIdx.z;
    const int tid = threadIdx.x;
    const int ocq = tid & 15, jg = tid >> 4;
    const int rr  = jg >> 3;                 // 0/1: which output row
    const int j0  = (jg & 7) * 16;           // 16 cols per thread
    const int oc0 = ocb*64 + ocq*4;
    const int h   = h0 + rr;
    const float* xb = x + (size_t)b*CC*NN;

    float acc[4][16];
    #pragma unroll
    for (int i=0;i<4;i++) {
        float bi = bd1[oc0+i] + bd3[oc0+i];
        #pragma unroll
        for (int j=0;j<16;j++) acc[i][j] = bi;
    }

    for (int cb=0; cb<CC; cb+=8) {
        __syncthreads();
        for (int i = tid; i < 8*4*132; i += 256) {
            int c8  = i / 528;
            int rem = i - c8*528;
            int r   = rem / 132;
            int col = rem - r*132;
            int hr  = h0 - 1 + r;
            int wc  = col - 1;
            float v = 0.0f;
            if (hr >= 0 && hr < HH && wc >= 0 && wc < WW)
                v = xb[(size_t)(cb + c8)*NN + hr*WW + wc];
            xsh[i] = v;
        }
        __syncthreads();
        #pragma unroll 1
        for (int c8=0;c8<8;c8++) {
            const int c = cb + c8;
            float w[4][9];
            #pragma unroll
            for (int i=0;i<4;i++) {
                const float4* wr = (const float4*)&wpack[(size_t)((oc0+i)*CC + c)*12];
                float4 a0 = wr[0], a1 = wr[1], a2 = wr[2];
                w[i][0]=a0.x; w[i][1]=a0.y; w[i][2]=a0.z; w[i][3]=a0.w;
                w[i][4]=a1.x; w[i][5]=a1.y; w[i][6]=a1.z; w[i][7]=a1.w;
                w[i][8]=a2.x;
            }
            float4 cur[3], nxt[3];
            #pragma unroll
            for (int ky=0;ky<3;ky++)
                cur[ky] = *(const float4*)&xsh[(c8*4 + rr + ky)*132 + j0];
            #pragma unroll
            for (int ch=0;ch<4;ch++) {
                #pragma unroll
                for (int ky=0;ky<3;ky++)
                    nxt[ky] = *(const float4*)&xsh[(c8*4 + rr + ky)*132 + j0 + ch*4 + 4];
                #pragma unroll
                for (int ky=0;ky<3;ky++) {
                    float wn[8] = {cur[ky].x, cur[ky].y, cur[ky].z, cur[ky].w,
                                   nxt[ky].x, nxt[ky].y, nxt[ky].z, nxt[ky].w};
                    #pragma unroll
                    for (int jj=0;jj<4;jj++) {
                        const int p = ch*4 + jj;
                        #pragma unroll
                        for (int i=0;i<4;i++) {
                            acc[i][p] = fmaf(w[i][ky*3+0], wn[jj],   acc[i][p]);
                            acc[i][p] = fmaf(w[i][ky*3+1], wn[jj+1], acc[i][p]);
                            acc[i][p] = fmaf(w[i][ky*3+2], wn[jj+2], acc[i][p]);
                        }
                    }
                }
                #pragma unroll
                for (int ky=0;ky<3;ky++) cur[ky] = nxt[ky];
            }
        }
    }
    const float g = gamma[0];
    #pragma unroll
    for (int i=0;i<4;i++) {
        float* orow = out + ((size_t)b*CC + oc0 + i)*NN + h*WW + j0;
        #pragma unroll
        for (int q=0;q<4;q++) {
            float4 o = *(float4*)&orow[4*q];
            o.x += g*acc[i][4*q+0]; o.y += g*acc[i][4*q+1];
            o.z += g*acc[i][4*q+2]; o.w += g*acc[i][4*q+3];
            *(float4*)&orow[4*q] = o;
        }
    }
}

extern "C" void kernel_launch(void* const* d_in, const int* in_sizes, int n_in,
                              void* d_out, int out_size, void* d_ws, size_t ws_size,
                              hipStream_t stream)
{
    const float* x     = (const float*)d_in[0];
    const float* wq    = (const float*)d_in[1];
    const float* bq    = (const float*)d_in[2];
    const float* wk    = (const float*)d_in[3];
    const float* bk    = (const float*)d_in[4];
    const float* wv    = (const float*)d_in[5];
    const float* bv    = (const float*)d_in[6];
    const float* wd1   = (const float*)d_in[7];
    const float* bd1   = (const float*)d_in[8];
    const float* wd3   = (const float*)d_in[9];
    const float* bd3   = (const float*)d_in[10];
    const float* gamma = (const float*)d_in[11];
    float* out = (float*)d_out;

    float* kp    = (float*)d_ws;                  // B*C*N   (64 MB)
    float* Qs    = kp + (size_t)BB*CC*NN;         // B*N
    float* Es    = Qs + (size_t)BB*NN;            // B*C
    float* rn    = Es + (size_t)BB*CC;            // B*N
    float* wpack = rn + (size_t)BB*NN;            // C*C*12  (3 MB)

    k_prep_w<<<dim3(CC*CC/256), 256, 0, stream>>>(wd1, wd3, wpack);
    k_qk   <<<dim3(NN/64, BB), 256, 0, stream>>>(x, wq, bq, wk, bk, kp, Qs);
    k_esum <<<dim3(BB*CC), 256, 0, stream>>>(kp, Qs, Es);
    k_norm <<<dim3(NN/256, BB), 256, 0, stream>>>(kp, Es, rn);
    k_vattn<<<dim3(NN/64, BB), 256, 0, stream>>>(x, wv, bv, kp, Es, rn, gamma, out);
    k_conv <<<dim3(CC/64, HH/2, BB), 256, 0, stream>>>(x, wpack, bd1, bd3, gamma, out);
}

// Round 2
// 834.620 us; speedup vs baseline: 2.7341x; 2.7341x over previous
//
#include <hip/hip_runtime.h>

#define BB 4
#define CC 256
#define HH 128
#define WW 128
#define NN (HH*WW)
#define EPSF 1e-10f

typedef __bf16 bf16x8 __attribute__((ext_vector_type(8)));
typedef float  f32x4  __attribute__((ext_vector_type(4)));

__device__ __forceinline__ float delu_f(float v) {
    // x>0: 10x+1 ; x<=0: exp(10x)
    return v > 0.0f ? fmaf(10.0f, v, 1.0f) : __expf(10.0f * v);
}

// ---------------- weight repack: wbf[t][oc][ic] = bf16(wd3[oc][ic][t] (+wd1 at center))
__global__ __launch_bounds__(256) void k_prep_wbf(const float* __restrict__ wd1,
                                                  const float* __restrict__ wd3,
                                                  __bf16* __restrict__ wbf)
{
    int idx = blockIdx.x * 256 + threadIdx.x;   // oc*256+ic
    if (idx >= CC*CC) return;
    float w9[9];
    #pragma unroll
    for (int k=0;k<9;k++) w9[k] = wd3[(size_t)idx*9 + k];
    w9[4] += wd1[idx];
    #pragma unroll
    for (int t=0;t<9;t++) wbf[(size_t)t*CC*CC + idx] = (__bf16)w9[t];
}

// ---------------- shared GEMM register tile: 4 oc x 16 pos, K=256, x tile in LDS (xs[256][64])
__device__ __forceinline__ void gemm_tile_256(const float* __restrict__ w,
                                              const float* __restrict__ bias,
                                              const float* xs, int oc0, int j0,
                                              float acc[4][16])
{
    #pragma unroll
    for (int i=0;i<4;i++) {
        float bv = bias[oc0+i];
        #pragma unroll
        for (int j=0;j<16;j++) acc[i][j] = bv;
    }
    for (int c=0;c<CC;c+=4) {
        float4 wr[4];
        #pragma unroll
        for (int i=0;i<4;i++) wr[i] = *(const float4*)&w[(size_t)(oc0+i)*CC + c];
        #pragma unroll
        for (int cc=0;cc<4;cc++) {
            const float4* xr = (const float4*)&xs[(c+cc)*64 + j0];
            float xv[16];
            #pragma unroll
            for (int q=0;q<4;q++) { float4 t = xr[q];
                xv[4*q]=t.x; xv[4*q+1]=t.y; xv[4*q+2]=t.z; xv[4*q+3]=t.w; }
            #pragma unroll
            for (int i=0;i<4;i++) {
                float wv = (cc==0)?wr[i].x:(cc==1)?wr[i].y:(cc==2)?wr[i].z:wr[i].w;
                #pragma unroll
                for (int j=0;j<16;j++) acc[i][j] = fmaf(wv, xv[j], acc[i][j]);
            }
        }
    }
}

// ---------------- q' and k' projections + Qs = sum_m delu(q); k' = delu(k) to ws
__global__ __launch_bounds__(256) void k_qk(const float* __restrict__ x,
    const float* __restrict__ wq, const float* __restrict__ bq,
    const float* __restrict__ wk, const float* __restrict__ bk,
    float* __restrict__ kp, float* __restrict__ Qs)
{
    __shared__ float xs[CC*64];
    const int n0 = blockIdx.x * 64;
    const int b  = blockIdx.y;
    const int tid = threadIdx.x;
    const float* xb = x + (size_t)b*CC*NN;
    for (int i = tid*4; i < CC*64; i += 1024) {
        int c = i >> 6, j = i & 63;
        *(float4*)&xs[i] = *(const float4*)&xb[(size_t)c*NN + n0 + j];
    }
    __syncthreads();
    const int ocq = tid & 63, jg = tid >> 6;
    const int oc0 = ocq*4, j0 = jg*16;
    float acc[4][16];

    // Q phase
    gemm_tile_256(wq, bq, xs, oc0, j0, acc);
    float qs[16];
    #pragma unroll
    for (int j=0;j<16;j++) {
        float s = delu_f(acc[0][j]) + delu_f(acc[1][j]) + delu_f(acc[2][j]) + delu_f(acc[3][j]);
        #pragma unroll
        for (int m=1; m<64; m<<=1) s += __shfl_xor(s, m, 64);
        qs[j] = s;   // full sum over all 256 channels (wave = 64 lanes x 4 oc each)
    }
    if ((tid & 63) == 0) {
        #pragma unroll
        for (int j=0;j<16;j++) Qs[(size_t)b*NN + n0 + j0 + j] = qs[j];
    }

    // K phase
    gemm_tile_256(wk, bk, xs, oc0, j0, acc);
    #pragma unroll
    for (int i=0;i<4;i++) {
        float* kr = kp + ((size_t)b*CC + oc0 + i)*NN + n0 + j0;
        #pragma unroll
        for (int q=0;q<4;q++) {
            float4 o;
            o.x = delu_f(acc[i][4*q+0]); o.y = delu_f(acc[i][4*q+1]);
            o.z = delu_f(acc[i][4*q+2]); o.w = delu_f(acc[i][4*q+3]);
            *(float4*)&kr[4*q] = o;
        }
    }
}

// ---------------- Esum[b,c] = sum_n Qs[b,n] * k'[b,c,n]
__global__ __launch_bounds__(256) void k_esum(const float* __restrict__ kp,
    const float* __restrict__ Qs, float* __restrict__ Es)
{
    const int c = blockIdx.x & (CC-1), b = blockIdx.x >> 8;
    const int tid = threadIdx.x;
    const float4* kr = (const float4*)(kp + ((size_t)b*CC + c)*NN);
    const float4* qr = (const float4*)(Qs + (size_t)b*NN);
    float s = 0.0f;
    for (int i = tid; i < NN/4; i += 256) {
        float4 kk = kr[i], qq = qr[i];
        s += kk.x*qq.x + kk.y*qq.y + kk.z*qq.z + kk.w*qq.w;
    }
    #pragma unroll
    for (int m=1; m<64; m<<=1) s += __shfl_xor(s, m, 64);
    __shared__ float red[4];
    if ((tid & 63) == 0) red[tid >> 6] = s;
    __syncthreads();
    if (tid == 0) Es[b*CC + c] = red[0] + red[1] + red[2] + red[3];
}

// ---------------- rnorm[b,n] = 1 / (sum_c Es[b,c]*k'[b,c,n] + eps)
__global__ __launch_bounds__(256) void k_norm(const float* __restrict__ kp,
    const float* __restrict__ Es, float* __restrict__ rn)
{
    const int b = blockIdx.y;
    const int n0 = blockIdx.x * 256;
    const int tid = threadIdx.x;
    __shared__ float es[CC];
    es[tid] = Es[b*CC + tid];
    __syncthreads();
    float a = 0.0f;
    const float* kb = kp + (size_t)b*CC*NN + n0 + tid;
    #pragma unroll 8
    for (int c=0;c<CC;c++) a = fmaf(es[c], kb[(size_t)c*NN], a);
    rn[(size_t)b*NN + n0 + tid] = 1.0f / (a + EPSF);
}

// ---------------- v projection + attention epilogue: out = x + g*Es*k'*v*rn
__global__ __launch_bounds__(256) void k_vattn(const float* __restrict__ x,
    const float* __restrict__ wv, const float* __restrict__ bv,
    const float* __restrict__ kp, const float* __restrict__ Es,
    const float* __restrict__ rn, const float* __restrict__ gamma,
    float* __restrict__ out)
{
    __shared__ float xs[CC*64];
    const int n0 = blockIdx.x * 64;
    const int b  = blockIdx.y;
    const int tid = threadIdx.x;
    const float* xb = x + (size_t)b*CC*NN;
    for (int i = tid*4; i < CC*64; i += 1024) {
        int c = i >> 6, j = i & 63;
        *(float4*)&xs[i] = *(const float4*)&xb[(size_t)c*NN + n0 + j];
    }
    __syncthreads();
    const int ocq = tid & 63, jg = tid >> 6;
    const int oc0 = ocq*4, j0 = jg*16;
    float acc[4][16];
    gemm_tile_256(wv, bv, xs, oc0, j0, acc);
    const float g = gamma[0];
    #pragma unroll
    for (int i=0;i<4;i++) {
        const int oc = oc0 + i;
        const float eg = Es[b*CC + oc] * g;
        const float* kr = kp + ((size_t)b*CC + oc)*NN + n0 + j0;
        const float* rr = rn + (size_t)b*NN + n0 + j0;
        const float* xr = xs + oc*64 + j0;
        float* orow = out + ((size_t)b*CC + oc)*NN + n0 + j0;
        #pragma unroll
        for (int q=0;q<4;q++) {
            float4 kk = *(const float4*)&kr[4*q];
            float4 rv = *(const float4*)&rr[4*q];
            float4 xv = *(const float4*)&xr[4*q];
            float4 o;
            o.x = fmaf(eg*kk.x*rv.x, acc[i][4*q+0], xv.x);
            o.y = fmaf(eg*kk.y*rv.y, acc[i][4*q+1], xv.y);
            o.z = fmaf(eg*kk.z*rv.z, acc[i][4*q+2], xv.z);
            o.w = fmaf(eg*kk.w*rv.w, acc[i][4*q+3], xv.w);
            *(float4*)&orow[4*q] = o;
        }
    }
}

// ---------------- 3x3 conv (+folded 1x1) via MFMA: out += g * (conv(x) + bias)
// block: 128 oc x 128 cols (one image row h); 4 waves in 2x2; wave = 64x64 = 4x4 frags
// LDS x tile: [ky 0..2][icq 0..3][col 0..131][8 ic] bf16 (b128-quantized, halo col 0/129)
__global__ __launch_bounds__(256) void k_conv_mfma(const float* __restrict__ x,
    const __bf16* __restrict__ wbf, const float* __restrict__ bd1,
    const float* __restrict__ bd3, const float* __restrict__ gamma,
    float* __restrict__ out)
{
    __shared__ __bf16 xs[3*4*132*8];
    const int ocb = blockIdx.x;       // 0..1
    const int h   = blockIdx.y;       // 0..127
    const int b   = blockIdx.z;
    const int tid = threadIdx.x;
    const int wid = tid >> 6, lane = tid & 63;
    const int wm = wid >> 1, wn = wid & 1;
    const int l15 = lane & 15, lq = lane >> 4;
    const int oc_base  = ocb*128 + wm*64;
    const int col_base = wn*64;
    const float* xb = x + (size_t)b*CC*NN;

    f32x4 acc[4][4] = {};

    for (int icb = 0; icb < 8; ++icb) {
        const int ic0 = icb*32;
        if (icb) __syncthreads();
        // halo cols 0 and 129 = image cols -1 / 128 -> zero
        if (tid < 96) {
            int ky = tid / 32, ic = tid % 32;
            int base = ((ky*4 + (ic>>3))*132)*8 + (ic&7);
            xs[base]          = (__bf16)0.0f;
            xs[base + 129*8]  = (__bf16)0.0f;
        }
        // main stage: 3 rows x 32 ic x 128 cols (fp32 -> bf16)
        for (int i = tid; i < 3072; i += 256) {
            int ky   = i >> 10;
            int rem  = i & 1023;
            int ic   = rem >> 5;
            int colq = rem & 31;
            int hr   = h - 1 + ky;
            float4 v = make_float4(0.f,0.f,0.f,0.f);
            if (hr >= 0 && hr < HH)
                v = *(const float4*)&xb[(size_t)(ic0+ic)*NN + hr*WW + colq*4];
            int base = ((ky*4 + (ic>>3))*132 + 1 + colq*4)*8 + (ic&7);
            xs[base]      = (__bf16)v.x;
            xs[base + 8]  = (__bf16)v.y;
            xs[base + 16] = (__bf16)v.z;
            xs[base + 24] = (__bf16)v.w;
        }
        __syncthreads();
        #pragma unroll
        for (int ky=0; ky<3; ky++) {
            #pragma unroll
            for (int kx=0; kx<3; kx++) {
                const int t = ky*3 + kx;
                bf16x8 af[4];
                #pragma unroll
                for (int f=0; f<4; f++)
                    af[f] = *(const bf16x8*)&wbf[(size_t)(t*CC + oc_base + f*16 + l15)*CC + ic0 + lq*8];
                bf16x8 bfr[4];
                #pragma unroll
                for (int nf=0; nf<4; nf++)
                    bfr[nf] = *(const bf16x8*)&xs[((ky*4 + lq)*132 + col_base + nf*16 + l15 + kx)*8];
                #pragma unroll
                for (int f=0; f<4; f++)
                    #pragma unroll
                    for (int nf=0; nf<4; nf++)
                        acc[f][nf] = __builtin_amdgcn_mfma_f32_16x16x32_bf16(af[f], bfr[nf], acc[f][nf], 0, 0, 0);
            }
        }
    }
    // epilogue: out += g*(acc + bias)
    const float g = gamma[0];
    #pragma unroll
    for (int f=0; f<4; f++) {
        #pragma unroll
        for (int r=0; r<4; r++) {
            const int oc = oc_base + f*16 + lq*4 + r;
            const float bias = bd1[oc] + bd3[oc];
            float* orow = out + ((size_t)b*CC + oc)*NN + h*WW;
            #pragma unroll
            for (int nf=0; nf<4; nf++) {
                const int w = col_base + nf*16 + l15;
                orow[w] += g*(acc[f][nf][r] + bias);
            }
        }
    }
}

extern "C" void kernel_launch(void* const* d_in, const int* in_sizes, int n_in,
                              void* d_out, int out_size, void* d_ws, size_t ws_size,
                              hipStream_t stream)
{
    const float* x     = (const float*)d_in[0];
    const float* wq    = (const float*)d_in[1];
    const float* bq    = (const float*)d_in[2];
    const float* wk    = (const float*)d_in[3];
    const float* bk    = (const float*)d_in[4];
    const float* wv    = (const float*)d_in[5];
    const float* bv    = (const float*)d_in[6];
    const float* wd1   = (const float*)d_in[7];
    const float* bd1   = (const float*)d_in[8];
    const float* wd3   = (const float*)d_in[9];
    const float* bd3   = (const float*)d_in[10];
    const float* gamma = (const float*)d_in[11];
    float* out = (float*)d_out;

    float*  kp  = (float*)d_ws;                   // B*C*N   (64 MB)
    float*  Qs  = kp + (size_t)BB*CC*NN;          // B*N
    float*  Es  = Qs + (size_t)BB*NN;             // B*C
    float*  rn  = Es + (size_t)BB*CC;             // B*N
    __bf16* wbf = (__bf16*)(rn + (size_t)BB*NN);  // [9][256][256] bf16 (1.2 MB)

    k_prep_wbf<<<dim3(CC*CC/256), 256, 0, stream>>>(wd1, wd3, wbf);
    k_qk      <<<dim3(NN/64, BB), 256, 0, stream>>>(x, wq, bq, wk, bk, kp, Qs);
    k_esum    <<<dim3(BB*CC), 256, 0, stream>>>(kp, Qs, Es);
    k_norm    <<<dim3(NN/256, BB), 256, 0, stream>>>(kp, Es, rn);
    k_vattn   <<<dim3(NN/64, BB), 256, 0, stream>>>(x, wv, bv, kp, Es, rn, gamma, out);
    k_conv_mfma<<<dim3(CC/128, HH, BB), 256, 0, stream>>>(x, wbf, bd1, bd3, gamma, out);
}

// Round 3
// 417.159 us; speedup vs baseline: 5.4701x; 2.0007x over previous
//
#include <hip/hip_runtime.h>

#define BB 4
#define CC 256
#define HH 128
#define WW 128
#define NN (HH*WW)
#define EPSF 1e-10f

typedef __bf16 bf16x8 __attribute__((ext_vector_type(8)));
typedef float  f32x4  __attribute__((ext_vector_type(4)));

__device__ __forceinline__ float delu_f(float v) {
    // x>0: 10x+1 ; x<=0: exp(10x)
    return v > 0.0f ? fmaf(10.0f, v, 1.0f) : __expf(10.0f * v);
}

// n-index XOR swizzle for the [cq][n][c8] LDS tile (write side == read side)
__device__ __forceinline__ int nswz(int n) { return n ^ ((n >> 3) & 7); }

// ---------------- weight packs: wq/wk/wv -> bf16; wd3 -> [t][oc][ic] bf16 with wd1 folded
__global__ __launch_bounds__(256) void k_prep(const float* __restrict__ wq,
    const float* __restrict__ wk, const float* __restrict__ wv,
    const float* __restrict__ wd1, const float* __restrict__ wd3,
    __bf16* __restrict__ wqb, __bf16* __restrict__ wkb, __bf16* __restrict__ wvb,
    __bf16* __restrict__ wbf)
{
    int idx = blockIdx.x * 256 + threadIdx.x;   // oc*256+ic
    if (idx >= CC*CC) return;
    wqb[idx] = (__bf16)wq[idx];
    wkb[idx] = (__bf16)wk[idx];
    wvb[idx] = (__bf16)wv[idx];
    float w9[9];
    #pragma unroll
    for (int k=0;k<9;k++) w9[k] = wd3[(size_t)idx*9 + k];
    w9[4] += wd1[idx];
    #pragma unroll
    for (int t=0;t<9;t++) wbf[(size_t)t*CC*CC + idx] = (__bf16)w9[t];
}

// ---------------- stage x[c][n0..n0+63] -> xs[cq][nswz(n)][c8] bf16 (32 KB)
__device__ __forceinline__ void stage_x64(const float* __restrict__ xb, int n0,
                                          __bf16* __restrict__ xs, int tid)
{
    for (int i = tid; i < 4096; i += 256) {
        int c = i >> 4, nq = i & 15;
        float4 v = *(const float4*)&xb[(size_t)c*NN + n0 + nq*4];
        int cq = c >> 3, c8 = c & 7;
        float vv[4] = {v.x, v.y, v.z, v.w};
        #pragma unroll
        for (int t=0;t<4;t++)
            xs[(cq*64 + nswz(nq*4+t))*8 + c8] = (__bf16)vv[t];
    }
}

// ---------------- one 64oc x 64n x 256c MFMA GEMM from staged xs
__device__ __forceinline__ void mfma_gemm_64x64(const __bf16* __restrict__ wb,
                                                const __bf16* __restrict__ xs,
                                                int oc_base, int l15, int lq,
                                                f32x4 acc[4][4])
{
    #pragma unroll
    for (int kb=0; kb<8; kb++) {
        bf16x8 af[4], bfr[4];
        #pragma unroll
        for (int f=0; f<4; f++)
            af[f] = *(const bf16x8*)&wb[(size_t)(oc_base + f*16 + l15)*CC + kb*32 + lq*8];
        #pragma unroll
        for (int nf=0; nf<4; nf++)
            bfr[nf] = *(const bf16x8*)&xs[((kb*4 + lq)*64 + nswz(nf*16 + l15))*8];
        #pragma unroll
        for (int f=0; f<4; f++)
            #pragma unroll
            for (int nf=0; nf<4; nf++)
                acc[f][nf] = __builtin_amdgcn_mfma_f32_16x16x32_bf16(af[f], bfr[nf], acc[f][nf], 0, 0, 0);
    }
}

// ---------------- q'/k' projections via MFMA + Qs = sum_m delu(q); k' -> kp
// block: 256 oc x 64 n; 4 waves (wave = 64 oc x 64 n)
__global__ __launch_bounds__(256) void k_qk_mfma(const float* __restrict__ x,
    const __bf16* __restrict__ wqb, const float* __restrict__ bq,
    const __bf16* __restrict__ wkb, const float* __restrict__ bk,
    float* __restrict__ kp, float* __restrict__ Qs)
{
    __shared__ __bf16 xs[32*64*8];
    __shared__ float Qpart[4][64];
    const int n0 = blockIdx.x * 64;
    const int b  = blockIdx.y;
    const int tid = threadIdx.x;
    const int wid = tid >> 6, lane = tid & 63;
    const int l15 = lane & 15, lq = lane >> 4;
    const int oc_base = wid*64;
    const float* xb = x + (size_t)b*CC*NN;

    stage_x64(xb, n0, xs, tid);
    __syncthreads();

    // --- Q phase ---
    f32x4 acc[4][4] = {};
    mfma_gemm_64x64(wqb, xs, oc_base, l15, lq, acc);
    #pragma unroll
    for (int nf=0; nf<4; nf++) {
        float s = 0.0f;
        #pragma unroll
        for (int f=0; f<4; f++)
            #pragma unroll
            for (int r=0; r<4; r++)
                s += delu_f(acc[f][nf][r] + bq[oc_base + f*16 + lq*4 + r]);
        s += __shfl_xor(s, 16);
        s += __shfl_xor(s, 32);
        if (lq == 0) Qpart[wid][nf*16 + l15] = s;
    }
    __syncthreads();
    if (tid < 64)
        Qs[(size_t)b*NN + n0 + tid] = Qpart[0][tid] + Qpart[1][tid] + Qpart[2][tid] + Qpart[3][tid];

    // --- K phase ---
    #pragma unroll
    for (int f=0; f<4; f++)
        #pragma unroll
        for (int nf=0; nf<4; nf++)
            acc[f][nf] = (f32x4){0.f,0.f,0.f,0.f};
    mfma_gemm_64x64(wkb, xs, oc_base, l15, lq, acc);
    #pragma unroll
    for (int f=0; f<4; f++) {
        #pragma unroll
        for (int r=0; r<4; r++) {
            const int oc = oc_base + f*16 + lq*4 + r;
            const float bias = bk[oc];
            float* kr = kp + ((size_t)b*CC + oc)*NN + n0;
            #pragma unroll
            for (int nf=0; nf<4; nf++)
                kr[nf*16 + l15] = delu_f(acc[f][nf][r] + bias);
        }
    }
}

// ---------------- Esum[b,c] = sum_n Qs[b,n] * k'[b,c,n]
__global__ __launch_bounds__(256) void k_esum(const float* __restrict__ kp,
    const float* __restrict__ Qs, float* __restrict__ Es)
{
    const int c = blockIdx.x & (CC-1), b = blockIdx.x >> 8;
    const int tid = threadIdx.x;
    const float4* kr = (const float4*)(kp + ((size_t)b*CC + c)*NN);
    const float4* qr = (const float4*)(Qs + (size_t)b*NN);
    float s = 0.0f;
    for (int i = tid; i < NN/4; i += 256) {
        float4 kk = kr[i], qq = qr[i];
        s += kk.x*qq.x + kk.y*qq.y + kk.z*qq.z + kk.w*qq.w;
    }
    #pragma unroll
    for (int m=1; m<64; m<<=1) s += __shfl_xor(s, m, 64);
    __shared__ float red[4];
    if ((tid & 63) == 0) red[tid >> 6] = s;
    __syncthreads();
    if (tid == 0) Es[b*CC + c] = red[0] + red[1] + red[2] + red[3];
}

// ---------------- rnorm[b,n] = 1 / (sum_c Es[b,c]*k'[b,c,n] + eps)
__global__ __launch_bounds__(256) void k_norm(const float* __restrict__ kp,
    const float* __restrict__ Es, float* __restrict__ rn)
{
    const int b = blockIdx.y;
    const int n0 = blockIdx.x * 256;
    const int tid = threadIdx.x;
    __shared__ float es[CC];
    es[tid] = Es[b*CC + tid];
    __syncthreads();
    float a = 0.0f;
    const float* kb = kp + (size_t)b*CC*NN + n0 + tid;
    #pragma unroll 8
    for (int c=0;c<CC;c++) a = fmaf(es[c], kb[(size_t)c*NN], a);
    rn[(size_t)b*NN + n0 + tid] = 1.0f / (a + EPSF);
}

// ---------------- v projection via MFMA + attention epilogue: out = x + g*Es*k'*v*rn
__global__ __launch_bounds__(256) void k_vattn_mfma(const float* __restrict__ x,
    const __bf16* __restrict__ wvb, const float* __restrict__ bv,
    const float* __restrict__ kp, const float* __restrict__ Es,
    const float* __restrict__ rn, const float* __restrict__ gamma,
    float* __restrict__ out)
{
    __shared__ __bf16 xs[32*64*8];
    const int n0 = blockIdx.x * 64;
    const int b  = blockIdx.y;
    const int tid = threadIdx.x;
    const int wid = tid >> 6, lane = tid & 63;
    const int l15 = lane & 15, lq = lane >> 4;
    const int oc_base = wid*64;
    const float* xb = x + (size_t)b*CC*NN;

    stage_x64(xb, n0, xs, tid);
    __syncthreads();

    f32x4 acc[4][4] = {};
    mfma_gemm_64x64(wvb, xs, oc_base, l15, lq, acc);

    const float g = gamma[0];
    float rv[4];
    #pragma unroll
    for (int nf=0; nf<4; nf++) rv[nf] = rn[(size_t)b*NN + n0 + nf*16 + l15];
    #pragma unroll
    for (int f=0; f<4; f++) {
        #pragma unroll
        for (int r=0; r<4; r++) {
            const int oc = oc_base + f*16 + lq*4 + r;
            const float eg = Es[b*CC + oc] * g;
            const float bias = bv[oc];
            const float* kr = kp + ((size_t)b*CC + oc)*NN + n0;
            const float* xr = x  + ((size_t)b*CC + oc)*NN + n0;
            float* orow = out + ((size_t)b*CC + oc)*NN + n0;
            #pragma unroll
            for (int nf=0; nf<4; nf++) {
                const int w = nf*16 + l15;
                orow[w] = fmaf(eg*kr[w]*rv[nf], acc[f][nf][r] + bias, xr[w]);
            }
        }
    }
}

// ---------------- 3x3 conv (+folded 1x1) via MFMA: out += g * (conv(x) + bias)
__global__ __launch_bounds__(256) void k_conv_mfma(const float* __restrict__ x,
    const __bf16* __restrict__ wbf, const float* __restrict__ bd1,
    const float* __restrict__ bd3, const float* __restrict__ gamma,
    float* __restrict__ out)
{
    __shared__ __bf16 xs[3*4*132*8];
    const int ocb = blockIdx.x;       // 0..1
    const int h   = blockIdx.y;       // 0..127
    const int b   = blockIdx.z;
    const int tid = threadIdx.x;
    const int wid = tid >> 6, lane = tid & 63;
    const int wm = wid >> 1, wn = wid & 1;
    const int l15 = lane & 15, lq = lane >> 4;
    const int oc_base  = ocb*128 + wm*64;
    const int col_base = wn*64;
    const float* xb = x + (size_t)b*CC*NN;

    f32x4 acc[4][4] = {};

    for (int icb = 0; icb < 8; ++icb) {
        const int ic0 = icb*32;
        if (icb) __syncthreads();
        if (tid < 96) {
            int ky = tid / 32, ic = tid % 32;
            int base = ((ky*4 + (ic>>3))*132)*8 + (ic&7);
            xs[base]          = (__bf16)0.0f;
            xs[base + 129*8]  = (__bf16)0.0f;
        }
        for (int i = tid; i < 3072; i += 256) {
            int ky   = i >> 10;
            int rem  = i & 1023;
            int ic   = rem >> 5;
            int colq = rem & 31;
            int hr   = h - 1 + ky;
            float4 v = make_float4(0.f,0.f,0.f,0.f);
            if (hr >= 0 && hr < HH)
                v = *(const float4*)&xb[(size_t)(ic0+ic)*NN + hr*WW + colq*4];
            int base = ((ky*4 + (ic>>3))*132 + 1 + colq*4)*8 + (ic&7);
            xs[base]      = (__bf16)v.x;
            xs[base + 8]  = (__bf16)v.y;
            xs[base + 16] = (__bf16)v.z;
            xs[base + 24] = (__bf16)v.w;
        }
        __syncthreads();
        #pragma unroll
        for (int ky=0; ky<3; ky++) {
            #pragma unroll
            for (int kx=0; kx<3; kx++) {
                const int t = ky*3 + kx;
                bf16x8 af[4];
                #pragma unroll
                for (int f=0; f<4; f++)
                    af[f] = *(const bf16x8*)&wbf[(size_t)(t*CC + oc_base + f*16 + l15)*CC + ic0 + lq*8];
                bf16x8 bfr[4];
                #pragma unroll
                for (int nf=0; nf<4; nf++)
                    bfr[nf] = *(const bf16x8*)&xs[((ky*4 + lq)*132 + col_base + nf*16 + l15 + kx)*8];
                #pragma unroll
                for (int f=0; f<4; f++)
                    #pragma unroll
                    for (int nf=0; nf<4; nf++)
                        acc[f][nf] = __builtin_amdgcn_mfma_f32_16x16x32_bf16(af[f], bfr[nf], acc[f][nf], 0, 0, 0);
            }
        }
    }
    const float g = gamma[0];
    #pragma unroll
    for (int f=0; f<4; f++) {
        #pragma unroll
        for (int r=0; r<4; r++) {
            const int oc = oc_base + f*16 + lq*4 + r;
            const float bias = bd1[oc] + bd3[oc];
            float* orow = out + ((size_t)b*CC + oc)*NN + h*WW;
            #pragma unroll
            for (int nf=0; nf<4; nf++) {
                const int w = col_base + nf*16 + l15;
                orow[w] += g*(acc[f][nf][r] + bias);
            }
        }
    }
}

extern "C" void kernel_launch(void* const* d_in, const int* in_sizes, int n_in,
                              void* d_out, int out_size, void* d_ws, size_t ws_size,
                              hipStream_t stream)
{
    const float* x     = (const float*)d_in[0];
    const float* wq    = (const float*)d_in[1];
    const float* bq    = (const float*)d_in[2];
    const float* wk    = (const float*)d_in[3];
    const float* bk    = (const float*)d_in[4];
    const float* wv    = (const float*)d_in[5];
    const float* bv    = (const float*)d_in[6];
    const float* wd1   = (const float*)d_in[7];
    const float* bd1   = (const float*)d_in[8];
    const float* wd3   = (const float*)d_in[9];
    const float* bd3   = (const float*)d_in[10];
    const float* gamma = (const float*)d_in[11];
    float* out = (float*)d_out;

    float*  kp  = (float*)d_ws;                    // B*C*N   (64 MB)
    float*  Qs  = kp + (size_t)BB*CC*NN;           // B*N
    float*  Es  = Qs + (size_t)BB*NN;              // B*C
    float*  rn  = Es + (size_t)BB*CC;              // B*N
    __bf16* wbf = (__bf16*)(rn + (size_t)BB*NN);   // [9][256][256] bf16
    __bf16* wqb = wbf + (size_t)9*CC*CC;           // [256][256] bf16
    __bf16* wkb = wqb + (size_t)CC*CC;
    __bf16* wvb = wkb + (size_t)CC*CC;

    k_prep      <<<dim3(CC*CC/256), 256, 0, stream>>>(wq, wk, wv, wd1, wd3, wqb, wkb, wvb, wbf);
    k_qk_mfma   <<<dim3(NN/64, BB), 256, 0, stream>>>(x, wqb, bq, wkb, bk, kp, Qs);
    k_esum      <<<dim3(BB*CC), 256, 0, stream>>>(kp, Qs, Es);
    k_norm      <<<dim3(NN/256, BB), 256, 0, stream>>>(kp, Es, rn);
    k_vattn_mfma<<<dim3(NN/64, BB), 256, 0, stream>>>(x, wvb, bv, kp, Es, rn, gamma, out);
    k_conv_mfma <<<dim3(CC/128, HH, BB), 256, 0, stream>>>(x, wbf, bd1, bd3, gamma, out);
}

// Round 4
// 302.736 us; speedup vs baseline: 7.5376x; 1.3780x over previous
//
#include <hip/hip_runtime.h>

#define BB 4
#define CC 256
#define HH 128
#define WW 128
#define NN (HH*WW)
#define EPSF 1e-10f

typedef __bf16 bf16x8 __attribute__((ext_vector_type(8)));
typedef float  f32x4  __attribute__((ext_vector_type(4)));

__device__ __forceinline__ float delu_f(float v) {
    // x>0: 10x+1 ; x<=0: exp(10x)
    return v > 0.0f ? fmaf(10.0f, v, 1.0f) : __expf(10.0f * v);
}

// ---------------- weight packs: wq/wk/wv -> bf16; wd3 -> [t][oc][ic] bf16 with wd1 folded
__global__ __launch_bounds__(256) void k_prep(const float* __restrict__ wq,
    const float* __restrict__ wk, const float* __restrict__ wv,
    const float* __restrict__ wd1, const float* __restrict__ wd3,
    __bf16* __restrict__ wqb, __bf16* __restrict__ wkb, __bf16* __restrict__ wvb,
    __bf16* __restrict__ wbf)
{
    int idx = blockIdx.x * 256 + threadIdx.x;   // oc*256+ic
    if (idx >= CC*CC) return;
    wqb[idx] = (__bf16)wq[idx];
    wkb[idx] = (__bf16)wk[idx];
    wvb[idx] = (__bf16)wv[idx];
    float w9[9];
    #pragma unroll
    for (int k=0;k<9;k++) w9[k] = wd3[(size_t)idx*9 + k];
    w9[4] += wd1[idx];
    #pragma unroll
    for (int t=0;t<9;t++) wbf[(size_t)t*CC*CC + idx] = (__bf16)w9[t];
}

// ---------------- stage x[c][n0..n0+63] -> xs[cq][n][c8] bf16 (32 KB), conflict-free b128 writes
__device__ __forceinline__ void stage_x64(const float* __restrict__ xb, int n0,
                                          __bf16* __restrict__ xs, int tid)
{
    for (int t = tid; t < 2048; t += 256) {
        int n = t & 63, cq = t >> 6;
        const float* p = xb + (size_t)(cq*8)*NN + n0 + n;
        bf16x8 v8;
        #pragma unroll
        for (int j=0;j<8;j++) v8[j] = (__bf16)p[(size_t)j*NN];
        *(bf16x8*)&xs[(size_t)(cq*64 + n)*8] = v8;
    }
}

// ---------------- one 64oc x 64n x 256c MFMA GEMM from staged xs
__device__ __forceinline__ void mfma_gemm_64x64(const __bf16* __restrict__ wb,
                                                const __bf16* __restrict__ xs,
                                                int oc_base, int l15, int lq,
                                                f32x4 acc[4][4])
{
    #pragma unroll
    for (int kb=0; kb<8; kb++) {
        bf16x8 af[4], bfr[4];
        #pragma unroll
        for (int f=0; f<4; f++)
            af[f] = *(const bf16x8*)&wb[(size_t)(oc_base + f*16 + l15)*CC + kb*32 + lq*8];
        #pragma unroll
        for (int nf=0; nf<4; nf++)
            bfr[nf] = *(const bf16x8*)&xs[(size_t)((kb*4 + lq)*64 + nf*16 + l15)*8];
        #pragma unroll
        for (int f=0; f<4; f++)
            #pragma unroll
            for (int nf=0; nf<4; nf++)
                acc[f][nf] = __builtin_amdgcn_mfma_f32_16x16x32_bf16(af[f], bfr[nf], acc[f][nf], 0, 0, 0);
    }
}

// ---------------- q'/k' projections via MFMA + Qs = sum_m delu(q); k' -> kp (bf16)
__global__ __launch_bounds__(256) void k_qk_mfma(const float* __restrict__ x,
    const __bf16* __restrict__ wqb, const float* __restrict__ bq,
    const __bf16* __restrict__ wkb, const float* __restrict__ bk,
    __bf16* __restrict__ kp, float* __restrict__ Qs)
{
    __shared__ __bf16 xs[32*64*8];
    __shared__ float Qpart[4][64];
    const int n0 = blockIdx.x * 64;
    const int b  = blockIdx.y;
    const int tid = threadIdx.x;
    const int wid = tid >> 6, lane = tid & 63;
    const int l15 = lane & 15, lq = lane >> 4;
    const int oc_base = wid*64;
    const float* xb = x + (size_t)b*CC*NN;

    stage_x64(xb, n0, xs, tid);
    __syncthreads();

    // --- Q phase ---
    f32x4 acc[4][4] = {};
    mfma_gemm_64x64(wqb, xs, oc_base, l15, lq, acc);
    #pragma unroll
    for (int nf=0; nf<4; nf++) {
        float s = 0.0f;
        #pragma unroll
        for (int f=0; f<4; f++)
            #pragma unroll
            for (int r=0; r<4; r++)
                s += delu_f(acc[f][nf][r] + bq[oc_base + f*16 + lq*4 + r]);
        s += __shfl_xor(s, 16);
        s += __shfl_xor(s, 32);
        if (lq == 0) Qpart[wid][nf*16 + l15] = s;
    }
    __syncthreads();
    if (tid < 64)
        Qs[(size_t)b*NN + n0 + tid] = Qpart[0][tid] + Qpart[1][tid] + Qpart[2][tid] + Qpart[3][tid];

    // --- K phase ---
    #pragma unroll
    for (int f=0; f<4; f++)
        #pragma unroll
        for (int nf=0; nf<4; nf++)
            acc[f][nf] = (f32x4){0.f,0.f,0.f,0.f};
    mfma_gemm_64x64(wkb, xs, oc_base, l15, lq, acc);
    #pragma unroll
    for (int f=0; f<4; f++) {
        #pragma unroll
        for (int r=0; r<4; r++) {
            const int oc = oc_base + f*16 + lq*4 + r;
            const float bias = bk[oc];
            __bf16* kr = kp + ((size_t)b*CC + oc)*NN + n0;
            #pragma unroll
            for (int nf=0; nf<4; nf++)
                kr[nf*16 + l15] = (__bf16)delu_f(acc[f][nf][r] + bias);
        }
    }
}

// ---------------- Esum[b,c] = sum_n Qs[b,n] * k'[b,c,n]
__global__ __launch_bounds__(256) void k_esum(const __bf16* __restrict__ kp,
    const float* __restrict__ Qs, float* __restrict__ Es)
{
    const int c = blockIdx.x & (CC-1), b = blockIdx.x >> 8;
    const int tid = threadIdx.x;
    const bf16x8* kr = (const bf16x8*)(kp + ((size_t)b*CC + c)*NN);
    const float4* qr = (const float4*)(Qs + (size_t)b*NN);
    float s = 0.0f;
    for (int i = tid; i < NN/8; i += 256) {
        bf16x8 kk = kr[i];
        float4 q0 = qr[2*i], q1 = qr[2*i+1];
        s += (float)kk[0]*q0.x + (float)kk[1]*q0.y + (float)kk[2]*q0.z + (float)kk[3]*q0.w
           + (float)kk[4]*q1.x + (float)kk[5]*q1.y + (float)kk[6]*q1.z + (float)kk[7]*q1.w;
    }
    #pragma unroll
    for (int m=1; m<64; m<<=1) s += __shfl_xor(s, m, 64);
    __shared__ float red[4];
    if ((tid & 63) == 0) red[tid >> 6] = s;
    __syncthreads();
    if (tid == 0) Es[b*CC + c] = red[0] + red[1] + red[2] + red[3];
}

// ---------------- v projection via MFMA + in-block denom + attention epilogue
// out = x + g * Es[oc] * k' * (v) * (1/(sum_c Es*k' + eps))
__global__ __launch_bounds__(256) void k_vattn_mfma(const float* __restrict__ x,
    const __bf16* __restrict__ wvb, const float* __restrict__ bv,
    const __bf16* __restrict__ kp, const float* __restrict__ Es,
    const float* __restrict__ gamma, float* __restrict__ out)
{
    __shared__ __bf16 xs[32*64*8];
    __shared__ float Dpart[4][64];
    __shared__ float rn_sh[64];
    const int n0 = blockIdx.x * 64;
    const int b  = blockIdx.y;
    const int tid = threadIdx.x;
    const int wid = tid >> 6, lane = tid & 63;
    const int l15 = lane & 15, lq = lane >> 4;
    const int oc_base = wid*64;
    const float* xb = x + (size_t)b*CC*NN;

    stage_x64(xb, n0, xs, tid);
    __syncthreads();

    f32x4 acc[4][4] = {};
    mfma_gemm_64x64(wvb, xs, oc_base, l15, lq, acc);

    // denom partials: sum over this thread's 16 oc rows of Es[oc]*k'[oc][w]
    float dpart[4] = {0.f,0.f,0.f,0.f};
    #pragma unroll
    for (int f=0; f<4; f++) {
        #pragma unroll
        for (int r=0; r<4; r++) {
            const int oc = oc_base + f*16 + lq*4 + r;
            const float e = Es[b*CC + oc];
            const __bf16* kr = kp + ((size_t)b*CC + oc)*NN + n0;
            #pragma unroll
            for (int nf=0; nf<4; nf++)
                dpart[nf] = fmaf(e, (float)kr[nf*16 + l15], dpart[nf]);
        }
    }
    #pragma unroll
    for (int nf=0; nf<4; nf++) {
        dpart[nf] += __shfl_xor(dpart[nf], 16);
        dpart[nf] += __shfl_xor(dpart[nf], 32);
        if (lq == 0) Dpart[wid][nf*16 + l15] = dpart[nf];
    }
    __syncthreads();
    if (tid < 64)
        rn_sh[tid] = 1.0f / (Dpart[0][tid] + Dpart[1][tid] + Dpart[2][tid] + Dpart[3][tid] + EPSF);
    __syncthreads();

    const float g = gamma[0];
    float rv[4];
    #pragma unroll
    for (int nf=0; nf<4; nf++) rv[nf] = rn_sh[nf*16 + l15];
    #pragma unroll
    for (int f=0; f<4; f++) {
        #pragma unroll
        for (int r=0; r<4; r++) {
            const int oc = oc_base + f*16 + lq*4 + r;
            const float eg = Es[b*CC + oc] * g;
            const float bias = bv[oc];
            const __bf16* kr = kp + ((size_t)b*CC + oc)*NN + n0;
            const float* xr  = x  + ((size_t)b*CC + oc)*NN + n0;
            float* orow = out + ((size_t)b*CC + oc)*NN + n0;
            #pragma unroll
            for (int nf=0; nf<4; nf++) {
                const int w = nf*16 + l15;
                orow[w] = fmaf(eg*(float)kr[w]*rv[nf], acc[f][nf][r] + bias, xr[w]);
            }
        }
    }
}

// ---------------- 3x3 conv (+folded 1x1) via MFMA, 2 output rows/block: out += g*(conv+bias)
// LDS: xs[r 0..3][icq 0..3][col 0..131][c8 0..7] bf16; staged rows hr = h0-1+r
__global__ __launch_bounds__(256,2) void k_conv_mfma(const float* __restrict__ x,
    const __bf16* __restrict__ wbf, const float* __restrict__ bd1,
    const float* __restrict__ bd3, const float* __restrict__ gamma,
    float* __restrict__ out)
{
    __shared__ __bf16 xs[4*4*132*8];
    const int ocb = blockIdx.x;       // 0..1
    const int h0  = blockIdx.y*2;     // output rows h0, h0+1
    const int b   = blockIdx.z;
    const int tid = threadIdx.x;
    const int wid = tid >> 6, lane = tid & 63;
    const int wm = wid >> 1, wn = wid & 1;
    const int l15 = lane & 15, lq = lane >> 4;
    const int oc_base  = ocb*128 + wm*64;
    const int col_base = wn*64;
    const float* xb = x + (size_t)b*CC*NN;

    f32x4 accA[4][4] = {};   // row h0
    f32x4 accB[4][4] = {};   // row h0+1

    for (int icb = 0; icb < 8; ++icb) {
        const int ic0 = icb*32;
        if (icb) __syncthreads();
        // stage 4 rows x 32 ic x cols 0..129 (col 0 / 129 are the +-1 halo)
        for (int t = tid; t < 2080; t += 256) {
            int col = t % 130;
            int rem = t / 130;
            int icq = rem & 3, r = rem >> 2;
            int hr = h0 - 1 + r;
            int wc = col - 1;
            bf16x8 v8 = {};
            if (hr >= 0 && hr < HH && wc >= 0 && wc < WW) {
                const float* p = xb + (size_t)(ic0 + icq*8)*NN + hr*WW + wc;
                #pragma unroll
                for (int j=0;j<8;j++) v8[j] = (__bf16)p[(size_t)j*NN];
            }
            *(bf16x8*)&xs[(size_t)((r*4 + icq)*132 + col)*8] = v8;
        }
        __syncthreads();
        // compute: staged row sr feeds accA (ky=sr) and accB (ky=sr-1)
        #pragma unroll
        for (int sr=0; sr<4; sr++) {
            #pragma unroll
            for (int kx=0; kx<3; kx++) {
                bf16x8 bfr[4];
                #pragma unroll
                for (int nf=0; nf<4; nf++)
                    bfr[nf] = *(const bf16x8*)&xs[(size_t)((sr*4 + lq)*132 + col_base + nf*16 + l15 + kx)*8];
                if (sr < 3) {
                    const int t = sr*3 + kx;
                    bf16x8 af[4];
                    #pragma unroll
                    for (int f=0; f<4; f++)
                        af[f] = *(const bf16x8*)&wbf[(size_t)(t*CC + oc_base + f*16 + l15)*CC + ic0 + lq*8];
                    #pragma unroll
                    for (int f=0; f<4; f++)
                        #pragma unroll
                        for (int nf=0; nf<4; nf++)
                            accA[f][nf] = __builtin_amdgcn_mfma_f32_16x16x32_bf16(af[f], bfr[nf], accA[f][nf], 0, 0, 0);
                }
                if (sr > 0) {
                    const int t = (sr-1)*3 + kx;
                    bf16x8 af[4];
                    #pragma unroll
                    for (int f=0; f<4; f++)
                        af[f] = *(const bf16x8*)&wbf[(size_t)(t*CC + oc_base + f*16 + l15)*CC + ic0 + lq*8];
                    #pragma unroll
                    for (int f=0; f<4; f++)
                        #pragma unroll
                        for (int nf=0; nf<4; nf++)
                            accB[f][nf] = __builtin_amdgcn_mfma_f32_16x16x32_bf16(af[f], bfr[nf], accB[f][nf], 0, 0, 0);
                }
            }
        }
    }
    const float g = gamma[0];
    #pragma unroll
    for (int f=0; f<4; f++) {
        #pragma unroll
        for (int r=0; r<4; r++) {
            const int oc = oc_base + f*16 + lq*4 + r;
            const float bias = bd1[oc] + bd3[oc];
            float* o0 = out + ((size_t)b*CC + oc)*NN + (size_t)h0*WW;
            float* o1 = o0 + WW;
            #pragma unroll
            for (int nf=0; nf<4; nf++) {
                const int w = col_base + nf*16 + l15;
                o0[w] += g*(accA[f][nf][r] + bias);
                o1[w] += g*(accB[f][nf][r] + bias);
            }
        }
    }
}

extern "C" void kernel_launch(void* const* d_in, const int* in_sizes, int n_in,
                              void* d_out, int out_size, void* d_ws, size_t ws_size,
                              hipStream_t stream)
{
    const float* x     = (const float*)d_in[0];
    const float* wq    = (const float*)d_in[1];
    const float* bq    = (const float*)d_in[2];
    const float* wk    = (const float*)d_in[3];
    const float* bk    = (const float*)d_in[4];
    const float* wv    = (const float*)d_in[5];
    const float* bv    = (const float*)d_in[6];
    const float* wd1   = (const float*)d_in[7];
    const float* bd1   = (const float*)d_in[8];
    const float* wd3   = (const float*)d_in[9];
    const float* bd3   = (const float*)d_in[10];
    const float* gamma = (const float*)d_in[11];
    float* out = (float*)d_out;

    __bf16* kp  = (__bf16*)d_ws;                   // B*C*N bf16 (33.5 MB)
    float*  Qs  = (float*)(kp + (size_t)BB*CC*NN); // B*N
    float*  Es  = Qs + (size_t)BB*NN;              // B*C
    __bf16* wbf = (__bf16*)(Es + (size_t)BB*CC);   // [9][256][256] bf16
    __bf16* wqb = wbf + (size_t)9*CC*CC;           // [256][256] bf16
    __bf16* wkb = wqb + (size_t)CC*CC;
    __bf16* wvb = wkb + (size_t)CC*CC;

    k_prep      <<<dim3(CC*CC/256), 256, 0, stream>>>(wq, wk, wv, wd1, wd3, wqb, wkb, wvb, wbf);
    k_qk_mfma   <<<dim3(NN/64, BB), 256, 0, stream>>>(x, wqb, bq, wkb, bk, kp, Qs);
    k_esum      <<<dim3(BB*CC), 256, 0, stream>>>(kp, Qs, Es);
    k_vattn_mfma<<<dim3(NN/64, BB), 256, 0, stream>>>(x, wvb, bv, kp, Es, gamma, out);
    k_conv_mfma <<<dim3(CC/128, HH/2, BB), 256, 0, stream>>>(x, wbf, bd1, bd3, gamma, out);
}